// Round 4
// baseline (131.893 us; speedup 1.0000x reference)
//
#include <hip/hip_runtime.h>
#include <hip/hip_bf16.h>

typedef __attribute__((ext_vector_type(4))) float f32x4;
typedef __attribute__((ext_vector_type(8))) __bf16 bf16x8;
typedef __attribute__((ext_vector_type(4))) unsigned int uint4v;

constexpr int M = 16384;
constexpr int N = 1024;
constexpr int K = 2048;
constexpr int BM = 256, BN = 256;  // block tile; K-tile = 64 (2x32 sub-tiles)
constexpr int NK2 = K / 64;        // 32 K-tiles
constexpr float BN_EPS = 1e-5f;
constexpr int TM2 = M / BM;  // 64 row-tiles (psum partials)

// async 16B global -> LDS (lds dest must be wave-uniform; HW adds lane*16)
#define GLOAD_LDS16(g, l)                                                      \
  __builtin_amdgcn_global_load_lds(                                            \
      (const __attribute__((address_space(1))) void*)(g),                      \
      (__attribute__((address_space(3))) void*)(l), 16, 0, 0)

#define SB0 __builtin_amdgcn_sched_barrier(0)
#define BARRIER __builtin_amdgcn_s_barrier()
#define VMC(n) asm volatile("s_waitcnt vmcnt(" #n ")" ::: "memory")
#define LGKM0 asm volatile("s_waitcnt lgkmcnt(0)" ::: "memory")

__device__ __forceinline__ unsigned sgnbf(float f) {
  return (f >= 0.f) ? 0x3F80u : 0xBF80u;
}
__global__ __launch_bounds__(256) void binw_kernel(
    const float* __restrict__ w, uint4v* __restrict__ wb) {
  size_t i = (size_t)blockIdx.x * 256 + threadIdx.x;
  const f32x4* win = (const f32x4*)w;
  f32x4 v0 = win[i * 2];
  f32x4 v1 = win[i * 2 + 1];
  uint4v o;
  o.x = sgnbf(v0[0]) | (sgnbf(v0[1]) << 16);
  o.y = sgnbf(v0[2]) | (sgnbf(v0[3]) << 16);
  o.z = sgnbf(v1[0]) | (sgnbf(v1[1]) << 16);
  o.w = sgnbf(v1[2]) | (sgnbf(v1[3]) << 16);
  wb[i] = o;
}

// ---- bf16 GEMM: 256^2 tile, 8 waves (8x1, each 32 rows x 256 cols) ----
// A (x, fp32) never touches LDS: each lane loads its own MFMA A-fragment
// (32B contiguous) global->reg one K-tile ahead, converts fp32->bf16 in
// VALU; compiler's per-use waitcnt handles the dependency. B (w_bin bf16)
// staged via gload_lds (pre-swizzled source) into 2-slot LDS, 64B rows,
// (row>>1)&3 chunk involution (R0-verified: 0 bank conflicts).
// ONE vmcnt(8)+barrier per K-tile: waves drift freely inside the tile;
// TLP hides LDS/cvt latency instead of barrier-lockstep draining.
// Epilogue: Y fp32 + fused per-column psum/psq partials (bnstats input
// is 256KB, not the 67MB Y).
__global__ __launch_bounds__(512, 2) void gemm_bin_kernel(
    const float* __restrict__ Af, const unsigned short* __restrict__ B,
    float* __restrict__ Y, float* __restrict__ psum, float* __restrict__ psq) {
  __shared__ unsigned short Bs[2][16384];  // 64 KiB: [slot][ks*8192+row*32+c*8]
  __shared__ float redsum[8][256];         // 8 KiB
  __shared__ float redsq[8][256];          // 8 KiB

  const int tid = threadIdx.x;
  const int wid = tid >> 6;
  const int lane = tid & 63;

  // T1: XCD swizzle (grid 256, %8==0): XCD owns contiguous tm range.
  const int bid = blockIdx.x;
  const int swz = (bid & 7) * 32 + (bid >> 3);
  const int tm = swz >> 2, tn = swz & 3;
  const size_t m0 = (size_t)tm * BM, n0 = (size_t)tn * BN;

  const int frow = lane & 15;  // fragment row/col within 16x16
  const int fcb = lane >> 4;   // k chunk 0..3
  // B frag read: row = nj*16+frow, chunk = fcb ^ ((frow>>1)&3) (involution)
  const int bbase = frow * 32 + ((fcb ^ ((frow >> 1) & 3)) * 8);

  // A: wave-private rows wid*32 + mi*16 + frow; k = kt*64 + ks*32 + fcb*8
  const float* pA = Af + (m0 + wid * 32 + frow) * (size_t)K + fcb * 8;

  // B staging: round rd (0..3): ks = rd>>1, rows (rd&1)*128 + wid*16 + l>>2;
  // global chunk = (l&3) ^ ((row>>1)&3) = (l&3) ^ ((l>>3)&3) (wave-invariant)
  const int gc = (lane & 3) ^ ((lane >> 3) & 3);
  const unsigned short* pBg =
      B + (n0 + wid * 16 + (lane >> 2)) * (size_t)K + gc * 8;

  f32x4 acc[2][16];
#pragma unroll
  for (int mi = 0; mi < 2; ++mi)
#pragma unroll
    for (int nj = 0; nj < 16; ++nj)
#pragma unroll
      for (int j = 0; j < 4; ++j) acc[mi][nj][j] = 0.f;

  // staged A fp32 regs (one K-tile: 2 mi x 2 ks x 8 floats)
  f32x4 xr0, xr1, xr2, xr3, xr4, xr5, xr6, xr7;

#define AL(ktv)                                                                \
  {                                                                            \
    const float* p0_ = pA + (size_t)(ktv)*64;                                  \
    const float* p1_ = pA + 16 * (size_t)K + (size_t)(ktv)*64;                 \
    xr0 = *(const f32x4*)(p0_);      /* mi0 ks0 */                             \
    xr1 = *(const f32x4*)(p0_ + 4);                                            \
    xr2 = *(const f32x4*)(p0_ + 32); /* mi0 ks1 */                             \
    xr3 = *(const f32x4*)(p0_ + 36);                                           \
    xr4 = *(const f32x4*)(p1_);      /* mi1 ks0 */                             \
    xr5 = *(const f32x4*)(p1_ + 4);                                            \
    xr6 = *(const f32x4*)(p1_ + 32); /* mi1 ks1 */                             \
    xr7 = *(const f32x4*)(p1_ + 36);                                           \
  }

#define CVT1(dst, ra, rb)                                                      \
  {                                                                            \
    bf16x8 v_;                                                                 \
    _Pragma("unroll") for (int j_ = 0; j_ < 4; ++j_) {                         \
      v_[j_] = (__bf16)(ra)[j_];                                               \
      v_[4 + j_] = (__bf16)(rb)[j_];                                           \
    }                                                                          \
    dst = v_;                                                                  \
  }

#define BG(rd, ktv, NS)                                                        \
  GLOAD_LDS16(                                                                 \
      pBg + (size_t)((rd)&1) * 128 * K + (size_t)(ktv)*64 + ((rd) >> 1) * 32,  \
      &Bs[NS][((rd) >> 1) * 8192 + (((rd)&1) * 128 + wid * 16) * 32])

#define PHASE(S, ks, njh, aA, aB)                                              \
  {                                                                            \
    bf16x8 b_[8];                                                              \
    _Pragma("unroll") for (int j_ = 0; j_ < 8; ++j_) b_[j_] =                  \
        *(const bf16x8*)&Bs[S][(ks)*8192 + ((njh)*8 + j_) * 512 + bbase];      \
    __builtin_amdgcn_s_setprio(1);                                             \
    _Pragma("unroll") for (int j_ = 0; j_ < 8; ++j_) {                         \
      acc[0][(njh)*8 + j_] = __builtin_amdgcn_mfma_f32_16x16x32_bf16(          \
          aA, b_[j_], acc[0][(njh)*8 + j_], 0, 0, 0);                          \
      acc[1][(njh)*8 + j_] = __builtin_amdgcn_mfma_f32_16x16x32_bf16(          \
          aB, b_[j_], acc[1][(njh)*8 + j_], 0, 0, 0);                          \
    }                                                                          \
    __builtin_amdgcn_s_setprio(0);                                             \
    SB0;                                                                       \
  }

  // One K-tile: cvt staged A, issue next tile's B gloads + A loads (B first
  // in queue -> VMC(8) at the end drains exactly B, leaves A in flight),
  // 4 MFMA phases (2 ks x 2 nj-halves), single read-drain + barrier.
#define ITER(S, NS, ktv, STG)                                                  \
  {                                                                            \
    bf16x8 a00, a01, a10, a11;                                                 \
    CVT1(a00, xr0, xr1);                                                       \
    CVT1(a01, xr2, xr3);                                                       \
    CVT1(a10, xr4, xr5);                                                       \
    CVT1(a11, xr6, xr7);                                                       \
    SB0;                                                                       \
    if (STG) {                                                                 \
      BG(0, (ktv) + 1, NS);                                                    \
      BG(1, (ktv) + 1, NS);                                                    \
      BG(2, (ktv) + 1, NS);                                                    \
      BG(3, (ktv) + 1, NS);                                                    \
      AL((ktv) + 1);                                                           \
      SB0;                                                                     \
    }                                                                          \
    PHASE(S, 0, 0, a00, a10);                                                  \
    PHASE(S, 0, 1, a00, a10);                                                  \
    PHASE(S, 1, 0, a01, a11);                                                  \
    PHASE(S, 1, 1, a01, a11);                                                  \
    if (STG) {                                                                 \
      LGKM0;                                                                   \
      VMC(8);                                                                  \
      BARRIER;                                                                 \
    }                                                                          \
  }

  // ---- prologue: stage tile 0 (B -> slot0, A -> regs) ----
  BG(0, 0, 0);
  BG(1, 0, 0);
  BG(2, 0, 0);
  BG(3, 0, 0);
  AL(0);
  SB0;
  VMC(8);  // drain B(0) x4 (oldest); A(0) x8 drain via cvt's auto-waits
  BARRIER;

  // ---- main loop: 32 K-tiles ----
  for (int kt = 0; kt < NK2 - 2; kt += 2) {
    ITER(0, 1, kt, 1);
    ITER(1, 0, kt + 1, 1);
  }
  ITER(0, 1, NK2 - 2, 1);  // kt=30 stages tile 31 -> slot1
  ITER(1, 0, NK2 - 1, 0);  // kt=31, no stage, no barrier

  // ---- epilogue 1: fused column partial stats from live accumulators ----
  // C/D layout: col = nj*16 + frow, row = wid*32 + mi*16 + fcb*4 + j
#pragma unroll
  for (int nj = 0; nj < 16; ++nj) {
    float s = 0.f, q = 0.f;
#pragma unroll
    for (int mi = 0; mi < 2; ++mi)
#pragma unroll
      for (int j = 0; j < 4; ++j) {
        float v = acc[mi][nj][j];
        s += v;
        q += v * v;
      }
    s += __shfl_xor(s, 16);  // reduce over fcb (lane bits 4-5)
    s += __shfl_xor(s, 32);
    q += __shfl_xor(q, 16);
    q += __shfl_xor(q, 32);
    if (fcb == 0) {
      redsum[wid][nj * 16 + frow] = s;
      redsq[wid][nj * 16 + frow] = q;
    }
  }
  __syncthreads();
  if (tid < BN) {
    float s = 0.f, q = 0.f;
#pragma unroll
    for (int w = 0; w < 8; ++w) {
      s += redsum[w][tid];
      q += redsq[w][tid];
    }
    psum[(size_t)tm * N + n0 + tid] = s;
    psq[(size_t)tm * N + n0 + tid] = q;
  }

  // ---- epilogue 2: store Y fp32 (raw pre-BN accumulators) ----
#pragma unroll
  for (int mi = 0; mi < 2; ++mi) {
    const size_t r0 = m0 + wid * 32 + mi * 16 + fcb * 4;
#pragma unroll
    for (int nj = 0; nj < 16; ++nj) {
      float* yp = Y + r0 * N + n0 + nj * 16 + frow;
#pragma unroll
      for (int j = 0; j < 4; ++j) yp[(size_t)j * N] = acc[mi][nj][j];
    }
  }
}

// ---- finalize BN stats -> per-column scale/shift ----
__global__ __launch_bounds__(256) void bnstats_kernel(
    const float* __restrict__ psum, const float* __restrict__ psq,
    const float* __restrict__ gamma, const float* __restrict__ beta,
    float* __restrict__ scale, float* __restrict__ shift) {
  const int c = blockIdx.x * 256 + threadIdx.x;
  float s = 0.f, q = 0.f;
  for (int i = 0; i < TM2; ++i) {
    s += psum[i * N + c];
    q += psq[i * N + c];
  }
  const float mean = s * (1.f / (float)M);
  const float var = q * (1.f / (float)M) - mean * mean;
  const float inv = rsqrtf(var + BN_EPS);
  const float sc = gamma[c] * inv;
  scale[c] = sc;
  shift[c] = beta[c] - mean * sc;
}

// ---- apply BN in place on fp32 Y (= d_out), 4 floats / thread ----
__global__ __launch_bounds__(256) void bnapply_kernel(
    float* __restrict__ Y, const float* __restrict__ scale,
    const float* __restrict__ shift) {
  const size_t i = (size_t)blockIdx.x * 256 + threadIdx.x;
  f32x4 y = ((const f32x4*)Y)[i];
  const int c = (int)((i * 4) & (N - 1));
  f32x4 sc = *(const f32x4*)&scale[c];
  f32x4 sh = *(const f32x4*)&shift[c];
  ((f32x4*)Y)[i] = y * sc + sh;
}

extern "C" void kernel_launch(void* const* d_in, const int* in_sizes, int n_in,
                              void* d_out, int out_size, void* d_ws,
                              size_t ws_size, hipStream_t stream) {
  const float* x = (const float*)d_in[0];
  const float* w = (const float*)d_in[1];
  // d_in[2] = bias: a per-column constant shift cancels exactly in BatchNorm
  const float* gamma = (const float*)d_in[3];
  const float* beta = (const float*)d_in[4];
  float* Y = (float*)d_out;  // y staged here fp32, normalized in place

  char* ws = (char*)d_ws;
  uint4v* wb = (uint4v*)ws;  // 4 MiB
  float* psum = (float*)(ws + (size_t)N * K * 2);
  float* psq = psum + (size_t)TM2 * N;  // 256 KiB each
  float* scale = psq + (size_t)TM2 * N;
  float* shift = scale + N;

  binw_kernel<<<(N * K / 8) / 256, 256, 0, stream>>>(w, wb);
  gemm_bin_kernel<<<(M / BM) * (N / BN), 512, 0, stream>>>(
      x, (const unsigned short*)wb, Y, psum, psq);
  bnstats_kernel<<<N / 256, 256, 0, stream>>>(psum, psq, gamma, beta, scale,
                                              shift);
  bnapply_kernel<<<(M * N / 4) / 256, 256, 0, stream>>>(Y, scale, shift);
}